// Round 5
// baseline (95.662 us; speedup 1.0000x reference)
//
#include <hip/hip_runtime.h>

#define B_DIM 512
#define C_DIM 512
#define BC (B_DIM * C_DIM)

constexpr int NCH[6]      = {6, 5, 5, 4, 4, 3};
constexpr int BASE[6]     = {0, 6, 21, 46, 74, 110};   // x BC elements
constexpr int FIRST_L1[6] = {0, 1, 1, 2, 2, 3};

// ws layout: symmetrized-compact cg per l1, ordered (L asc, M asc, pair asc)
static const int WS_BASE_H[6] = {0, 1, 55, 430, 1438, 3058};  // floats

struct PrepArgs {
    const float* src[27];
    int dst[27];
    int dim[27];     // d = 2*l1+1
    int twoLp1[27];  // 2*L+1
};

// Symmetrize cg into compact triangular form in ws.
// cgs[M, p(a<=b)] = cg[M,a,b] + cg[M,b,a]  (a<b);  cg[M,a,a] on diagonal.
__global__ void prep_kernel(PrepArgs pa, float* __restrict__ ws) {
    const int j = blockIdx.x;
    const float* __restrict__ cg = pa.src[j];
    const int d = pa.dim[j];
    const int NP = d * (d + 1) / 2;
    const int total = pa.twoLp1[j] * NP;
    for (int e = threadIdx.x; e < total; e += blockDim.x) {
        const int M = e / NP;
        const int p = e - M * NP;
        int na = 0, rem = p;
        while (rem >= d - na) { rem -= d - na; ++na; }
        const int nb = na + rem;
        float v = cg[(M * d + na) * d + nb];
        if (na != nb) v += cg[(M * d + nb) * d + na];
        ws[pa.dst[j] + e] = v;
    }
}

// Block handles (b, i0..i0+255). All global traffic via LDS, fully coalesced.
template <int L1>
__device__ __forceinline__ void tp_body(const float* __restrict__ x,
                                        const float* __restrict__ cgs,
                                        float* __restrict__ out, int blk,
                                        float* __restrict__ xs,
                                        float* __restrict__ os) {
    constexpr int d    = 2 * L1 + 1;
    constexpr int NP   = d * (d + 1) / 2;
    constexpr int Lmax = (2 * L1 < 5) ? 2 * L1 : 5;

    const int tid = (int)threadIdx.x;
    const int b   = blk >> 1;
    const int i0  = (blk & 1) << 8;

    // ---- stage x tile: 256*d contiguous floats, float4-coalesced ----
    {
        const float4* __restrict__ src4 =
            (const float4*)(x + (size_t)(b * C_DIM + i0) * d);
        float4* __restrict__ xs4 = (float4*)xs;
        constexpr int NV4 = 64 * d;           // (256*d)/4
#pragma unroll
        for (int e0 = 0; e0 < NV4; e0 += 256) {
            const int e = e0 + tid;
            if (e < NV4) xs4[e] = src4[e];
        }
    }
    __syncthreads();

    float xv[d];
#pragma unroll
    for (int m = 0; m < d; ++m) xv[m] = xs[tid * d + m];

    // ---- per output degree L: compute into LDS, coalesced copy out ----
#pragma unroll
    for (int L = 0; L <= Lmax; ++L) {
        const int twoLp1 = 2 * L + 1;        // compile-time after unroll
        const int co0    = L * L * NP;       // cumulative (2L'+1)*NP for L'<L
        float acc[11];
#pragma unroll
        for (int M = 0; M < twoLp1; ++M) acc[M] = 0.0f;

#pragma unroll
        for (int a = 0; a < d; ++a) {
#pragma unroll
            for (int bb = a; bb < d; ++bb) {
                const float op = xv[a] * xv[bb];
                const int p = a * d - a * (a - 1) / 2 + (bb - a);
#pragma unroll
                for (int M = 0; M < twoLp1; ++M)
                    acc[M] = fmaf(cgs[co0 + M * NP + p], op, acc[M]);
            }
        }

#pragma unroll
        for (int M = 0; M < twoLp1; ++M) os[tid * twoLp1 + M] = acc[M];
        __syncthreads();

        const int chunk = L1 - FIRST_L1[L];
        float* __restrict__ dst = out + (size_t)BASE[L] * BC +
            ((size_t)(b * NCH[L] + chunk) * C_DIM + i0) * twoLp1;
        const float4* __restrict__ os4 = (const float4*)os;
        float4* __restrict__ dst4 = (float4*)dst;
        const int nv4 = 64 * twoLp1;         // (256*twoLp1)/4
#pragma unroll
        for (int e0 = 0; e0 < 64 * 11; e0 += 256) {
            const int e = e0 + tid;
            if (e < nv4) dst4[e] = os4[e];
        }
        __syncthreads();
    }
}

// One fused launch; parts ordered by descending work so heavy blocks start first.
__global__ __launch_bounds__(256) void tp_all(
    const float* __restrict__ x0, const float* __restrict__ x1,
    const float* __restrict__ x2, const float* __restrict__ x3,
    const float* __restrict__ x4, const float* __restrict__ x5,
    const float* __restrict__ ws, float* __restrict__ out) {
    __shared__ __align__(16) float xs[256 * 11];
    __shared__ __align__(16) float os[256 * 11];
    const int part = blockIdx.x >> 10;   // 1024 blocks per part
    const int blk  = blockIdx.x & 1023;
    switch (part) {
        case 0:  tp_body<5>(x5, ws + 3058, out, blk, xs, os); break;
        case 1:  tp_body<4>(x4, ws + 1438, out, blk, xs, os); break;
        case 2:  tp_body<3>(x3, ws + 430,  out, blk, xs, os); break;
        case 3:  tp_body<2>(x2, ws + 55,   out, blk, xs, os); break;
        case 4:  tp_body<1>(x1, ws + 1,    out, blk, xs, os); break;
        default: tp_body<0>(x0, ws + 0,    out, blk, xs, os); break;
    }
}

extern "C" void kernel_launch(void* const* d_in, const int* in_sizes, int n_in,
                              void* d_out, int out_size, void* d_ws, size_t ws_size,
                              hipStream_t stream) {
    (void)in_sizes; (void)n_in; (void)out_size; (void)ws_size;

    PrepArgs pa;
    int j = 0;
    for (int l1 = 0; l1 <= 5; ++l1) {
        const int d = 2 * l1 + 1;
        const int NP = d * (d + 1) / 2;
        const int Lmax = (2 * l1 < 5) ? 2 * l1 : 5;
        for (int L = 0; L <= Lmax; ++L) {
            pa.src[j]    = (const float*)d_in[6 + j];
            pa.dst[j]    = WS_BASE_H[l1] + L * L * NP;
            pa.dim[j]    = d;
            pa.twoLp1[j] = 2 * L + 1;
            ++j;
        }
    }

    float* ws = (float*)d_ws;
    hipLaunchKernelGGL(prep_kernel, dim3(27), dim3(256), 0, stream, pa, ws);
    hipLaunchKernelGGL(tp_all, dim3(6 * 1024), dim3(256), 0, stream,
                       (const float*)d_in[0], (const float*)d_in[1],
                       (const float*)d_in[2], (const float*)d_in[3],
                       (const float*)d_in[4], (const float*)d_in[5],
                       (const float*)ws, (float*)d_out);
}

// Round 6
// 81.127 us; speedup vs baseline: 1.1792x; 1.1792x over previous
//
#include <hip/hip_runtime.h>

typedef _Float16 half8 __attribute__((ext_vector_type(8)));
typedef float f32x4 __attribute__((ext_vector_type(4)));

#define B_DIM 512
#define C_DIM 512
#define BC (B_DIM * C_DIM)

constexpr int NCH[6]      = {6, 5, 5, 4, 4, 3};
constexpr int BASE[6]     = {0, 6, 21, 46, 74, 110};   // x BC elements
constexpr int FIRST_L1[6] = {0, 1, 1, 2, 2, 3};

// frag-table base (in frags of 512 f16) per l1: counts {1:1, 2:2, 3:3, 4:6, 5:9}
// bases: l1=1:0, l1=2:1, l1=3:3, l1=4:6, l1=5:12 ; total 21 frags = 21.5 KB in ws

// triangular pair decode: p -> (a, b) with a<=b, p = a*d - a(a-1)/2 + (b-a)
constexpr int pair_a(int p, int d) {
    int a = 0, rem = p;
    while (rem >= d - a) { rem -= d - a; ++a; }
    return a;
}
constexpr int pair_b(int p, int d) {
    int a = 0, rem = p;
    while (rem >= d - a) { rem -= d - a; ++a; }
    return a + rem;
}

struct PrepArgs {
    const float* cg[5][6];   // [l1-1][L]
    int l1[21], ks[21], nt[21];
};

// Build fp16 B-fragments in exact MFMA lane layout, zero-padded.
// B[k][n] = cgs[n][p] with n = L^2 + M, p triangular pair index;
// frag elem (lane, j): n = nt*16 + (lane&15), k = (lane>>4)*8 + j, p = ks*32 + k.
__global__ void prep_frags(PrepArgs pa, _Float16* __restrict__ wsf) {
    const int f  = blockIdx.x;                 // global frag id, grid = 21
    const int l1 = pa.l1[f], ks = pa.ks[f], nt = pa.nt[f];
    const int d = 2 * l1 + 1, NP = d * (d + 1) / 2;
    const int Lmax = (2 * l1 < 5) ? 2 * l1 : 5;
    const int Ntot = (Lmax + 1) * (Lmax + 1);
    const int e = (int)threadIdx.x;            // 0..511
    const int lane = e >> 3, j = e & 7;
    const int n = nt * 16 + (lane & 15);
    const int p = ks * 32 + (lane >> 4) * 8 + j;
    float v = 0.f;
    if (n < Ntot && p < NP) {
        int L = 0;
        while ((L + 1) * (L + 1) <= n) ++L;
        const int M = n - L * L;
        int a = 0, rem = p;
        while (rem >= d - a) { rem -= d - a; ++a; }
        const int bb = a + rem;
        const float* cg = pa.cg[l1 - 1][L];
        v = cg[(M * d + a) * d + bb];          // cg[M][n=a][m=b]
        if (a != bb) v += cg[(M * d + bb) * d + a];
    }
    wsf[(size_t)f * 512 + e] = (_Float16)v;
}

template <int L1>
__device__ __forceinline__ void tp_mfma(const float* __restrict__ x,
                                        const _Float16* __restrict__ wsf,
                                        float* __restrict__ out,
                                        int blk, _Float16* __restrict__ Alds) {
    constexpr int d    = 2 * L1 + 1;
    constexpr int NP   = d * (d + 1) / 2;
    constexpr int Lmax = (2 * L1 < 5) ? 2 * L1 : 5;
    constexpr int Ntot = (Lmax + 1) * (Lmax + 1);
    constexpr int KS   = (NP + 31) / 32;       // K-steps of 32
    constexpr int NT   = (Ntot + 15) / 16;     // N-tiles of 16
    constexpr int AST  = 40;                   // A row stride in f16 (80B: bank-spread)

    const int tid = (int)threadIdx.x, lane = tid & 63, w = tid >> 6;
    const int t0 = blk << 8;                   // 256 rows per block
    const int b = blk >> 1, i0 = (blk & 1) << 8;

    // per-thread x row (d floats, L2-absorbed strided read)
    float xv[d];
    const float* xp = x + (size_t)(t0 + tid) * d;
#pragma unroll
    for (int m = 0; m < d; ++m) xv[m] = xp[m];

    // preload B fragments (coalesced 16B/lane)
    half8 bf[KS * NT];
#pragma unroll
    for (int f = 0; f < KS * NT; ++f)
        bf[f] = *(const half8*)(wsf + (size_t)f * 512 + lane * 8);

    const f32x4 zero = {0.f, 0.f, 0.f, 0.f};
    f32x4 acc[4][NT];
#pragma unroll
    for (int q = 0; q < 4; ++q)
#pragma unroll
        for (int nt = 0; nt < NT; ++nt) acc[q][nt] = zero;

#pragma unroll
    for (int ks = 0; ks < KS; ++ks) {
        // products for this K-slice, fp16-converted, zero-padded
        half8 ph[4];
#pragma unroll
        for (int g = 0; g < 4; ++g) {
#pragma unroll
            for (int j = 0; j < 8; ++j) {
                const int p = ks * 32 + g * 8 + j;   // compile-time after unroll
                float v = 0.f;
                if (p < NP) v = xv[pair_a(p, d)] * xv[pair_b(p, d)];
                ph[g][j] = (_Float16)v;
            }
        }
        // write own row (wave-private slice of A: rows [w*64, w*64+64))
        _Float16* ar = Alds + tid * AST;
#pragma unroll
        for (int g = 0; g < 4; ++g) *(half8*)(ar + g * 8) = ph[g];
        // no __syncthreads needed: each wave reads only rows it wrote;
        // compiler inserts lgkmcnt for the ds_write->ds_read dependency.
#pragma unroll
        for (int q = 0; q < 4; ++q) {
            const int row = (w * 4 + q) * 16 + (lane & 15);
            const half8 af = *(const half8*)(Alds + row * AST + (lane >> 4) * 8);
#pragma unroll
            for (int nt = 0; nt < NT; ++nt)
                acc[q][nt] = __builtin_amdgcn_mfma_f32_16x16x32_f16(
                    af, bf[ks * NT + nt], acc[q][nt], 0, 0, 0);
        }
    }

    // epilogue: D layout col=lane&15 (n), row=(lane>>4)*4+r (i within tile)
#pragma unroll
    for (int nt = 0; nt < NT; ++nt) {
        const int n = nt * 16 + (lane & 15);
        int L = 0;
#pragma unroll
        for (int s = 1; s <= 5; ++s) L += (n >= s * s) ? 1 : 0;
        const bool valid = n < Ntot;
        const int M = n - L * L;
        const int stride = 2 * L + 1;
        const int chunk = L1 - FIRST_L1[L];    // >=0 whenever valid
        float* obase = out + (size_t)BASE[L] * BC +
            (long long)(b * NCH[L] + chunk) * C_DIM * stride + M;
#pragma unroll
        for (int q = 0; q < 4; ++q) {
            const int ib = i0 + (w * 4 + q) * 16 + ((lane >> 4) << 2);
#pragma unroll
            for (int r = 0; r < 4; ++r)
                if (valid) obase[(long long)(ib + r) * stride] = acc[q][nt][r];
        }
    }
}

__global__ __launch_bounds__(256) void tp_all(
    const float* __restrict__ x0, const float* __restrict__ x1,
    const float* __restrict__ x2, const float* __restrict__ x3,
    const float* __restrict__ x4, const float* __restrict__ x5,
    const float* __restrict__ cg00, const _Float16* __restrict__ wsf,
    float* __restrict__ out) {
    __shared__ _Float16 Alds[256 * 40];        // 20 KB
    const int part = (int)blockIdx.x >> 10;    // 1024 blocks per part, heavy first
    const int blk  = (int)blockIdx.x & 1023;
    switch (part) {
        case 0: tp_mfma<5>(x5, wsf + 12 * 512, out, blk, Alds); break;
        case 1: tp_mfma<4>(x4, wsf + 6 * 512,  out, blk, Alds); break;
        case 2: tp_mfma<3>(x3, wsf + 3 * 512,  out, blk, Alds); break;
        case 3: tp_mfma<2>(x2, wsf + 1 * 512,  out, blk, Alds); break;
        case 4: tp_mfma<1>(x1, wsf + 0,        out, blk, Alds); break;
        default: {                              // l1 = 0: out = c00 * x0^2
            const int t = (blk << 8) + (int)threadIdx.x;
            const float v = x0[t];
            const int b = t >> 9, i = t & 511;
            out[(size_t)b * 3072 + i] = cg00[0] * v * v;
        } break;
    }
}

extern "C" void kernel_launch(void* const* d_in, const int* in_sizes, int n_in,
                              void* d_out, int out_size, void* d_ws, size_t ws_size,
                              hipStream_t stream) {
    (void)in_sizes; (void)n_in; (void)out_size; (void)ws_size;

    PrepArgs pa{};
    int idx = 6;
    for (int l1 = 0; l1 <= 5; ++l1) {
        const int Lmax = (2 * l1 < 5) ? 2 * l1 : 5;
        for (int L = 0; L <= Lmax; ++L) {
            if (l1 >= 1) pa.cg[l1 - 1][L] = (const float*)d_in[idx];
            ++idx;
        }
    }
    int f = 0;
    for (int l1 = 1; l1 <= 5; ++l1) {
        const int d = 2 * l1 + 1, NP = d * (d + 1) / 2;
        const int Lmax = (2 * l1 < 5) ? 2 * l1 : 5;
        const int Ntot = (Lmax + 1) * (Lmax + 1);
        const int KS = (NP + 31) / 32, NT = (Ntot + 15) / 16;
        for (int ks = 0; ks < KS; ++ks)
            for (int nt = 0; nt < NT; ++nt) {
                pa.l1[f] = l1; pa.ks[f] = ks; pa.nt[f] = nt; ++f;
            }
    }
    // f == 21 frags -> 21.5 KB fp16 table in ws

    hipLaunchKernelGGL(prep_frags, dim3(21), dim3(512), 0, stream,
                       pa, (_Float16*)d_ws);
    hipLaunchKernelGGL(tp_all, dim3(6 * 1024), dim3(256), 0, stream,
                       (const float*)d_in[0], (const float*)d_in[1],
                       (const float*)d_in[2], (const float*)d_in[3],
                       (const float*)d_in[4], (const float*)d_in[5],
                       (const float*)d_in[6], (const _Float16*)d_ws,
                       (float*)d_out);
}

// Round 9
// 66.925 us; speedup vs baseline: 1.4294x; 1.2122x over previous
//
#include <hip/hip_runtime.h>

typedef _Float16 half8 __attribute__((ext_vector_type(8)));
typedef float f32x4 __attribute__((ext_vector_type(4)));

#define B_DIM 512
#define C_DIM 512
#define BC (B_DIM * C_DIM)

constexpr int NCH[6]      = {6, 5, 5, 4, 4, 3};
constexpr int BASE[6]     = {0, 6, 21, 46, 74, 110};   // x BC elements
constexpr int FIRST_L1[6] = {0, 1, 1, 2, 2, 3};

// triangular pair decode: p -> (a, b) with a<=b
constexpr int pair_a(int p, int d) {
    int a = 0, rem = p;
    while (rem >= d - a) { rem -= d - a; ++a; }
    return a;
}
constexpr int pair_b(int p, int d) {
    int a = 0, rem = p;
    while (rem >= d - a) { rem -= d - a; ++a; }
    return a + rem;
}

struct PrepArgs {
    const float* cg[5][6];   // [l1-1][L]
    int l1[21], ks[21], nt[21];
};

// Build fp16 B-fragments in exact MFMA lane layout, zero-padded.
// frag elem (lane, j): n = nt*16 + (lane&15), k = (lane>>4)*8 + j, p = ks*32 + k.
__global__ void prep_frags(PrepArgs pa, _Float16* __restrict__ wsf) {
    const int f  = blockIdx.x;                 // global frag id, grid = 21
    const int l1 = pa.l1[f], ks = pa.ks[f], nt = pa.nt[f];
    const int d = 2 * l1 + 1, NP = d * (d + 1) / 2;
    const int Lmax = (2 * l1 < 5) ? 2 * l1 : 5;
    const int Ntot = (Lmax + 1) * (Lmax + 1);
    const int e = (int)threadIdx.x;            // 0..511
    const int lane = e >> 3, j = e & 7;
    const int n = nt * 16 + (lane & 15);
    const int p = ks * 32 + (lane >> 4) * 8 + j;
    float v = 0.f;
    if (n < Ntot && p < NP) {
        int L = 0;
        while ((L + 1) * (L + 1) <= n) ++L;
        const int M = n - L * L;
        int a = 0, rem = p;
        while (rem >= d - a) { rem -= d - a; ++a; }
        const int bb = a + rem;
        const float* cg = pa.cg[l1 - 1][L];
        v = cg[(M * d + a) * d + bb];
        if (a != bb) v += cg[(M * d + bb) * d + a];
    }
    wsf[(size_t)f * 512 + e] = (_Float16)v;
}

template <int L1>
__device__ __forceinline__ void tp_mfma(const float* __restrict__ x,
                                        const _Float16* __restrict__ wsf,
                                        float* __restrict__ out,
                                        int blk, _Float16* __restrict__ Alds,
                                        float* __restrict__ os) {
    constexpr int d    = 2 * L1 + 1;
    constexpr int NP   = d * (d + 1) / 2;
    constexpr int Lmax = (2 * L1 < 5) ? 2 * L1 : 5;
    constexpr int Ntot = (Lmax + 1) * (Lmax + 1);
    constexpr int KS   = (NP + 31) / 32;       // K-steps of 32
    constexpr int NT   = (Ntot + 15) / 16;     // N-tiles of 16
    constexpr int AST  = 40;                   // A row stride in f16 (80 B)

    const int tid = (int)threadIdx.x, lane = tid & 63, w = tid >> 6;
    const int t0 = blk << 8;                   // 256 rows per block
    const int b = blk >> 1, i0 = (blk & 1) << 8;

    // per-thread x row (round-6 verified direct loads)
    float xv[d];
    const float* xp = x + (size_t)(t0 + tid) * d;
#pragma unroll
    for (int m = 0; m < d; ++m) xv[m] = xp[m];

    // preload B fragments (coalesced 16 B/lane)
    half8 bf[KS * NT];
#pragma unroll
    for (int f = 0; f < KS * NT; ++f)
        bf[f] = *(const half8*)(wsf + (size_t)f * 512 + lane * 8);

    const f32x4 zero = {0.f, 0.f, 0.f, 0.f};
    f32x4 acc[4][NT];
#pragma unroll
    for (int q = 0; q < 4; ++q)
#pragma unroll
        for (int nt = 0; nt < NT; ++nt) acc[q][nt] = zero;

#pragma unroll
    for (int ks = 0; ks < KS; ++ks) {
        half8 ph[4];
#pragma unroll
        for (int g = 0; g < 4; ++g) {
#pragma unroll
            for (int j = 0; j < 8; ++j) {
                const int p = ks * 32 + g * 8 + j;
                float v = 0.f;
                if (p < NP) v = xv[pair_a(p, d)] * xv[pair_b(p, d)];
                ph[g][j] = (_Float16)v;
            }
        }
        _Float16* ar = Alds + tid * AST;
#pragma unroll
        for (int g = 0; g < 4; ++g) *(half8*)(ar + g * 8) = ph[g];
        // wave-private rows: in-order DS per wave, verified in round 6
#pragma unroll
        for (int q = 0; q < 4; ++q) {
            const int row = (w * 4 + q) * 16 + (lane & 15);
            const half8 af = *(const half8*)(Alds + row * AST + (lane >> 4) * 8);
#pragma unroll
            for (int nt = 0; nt < NT; ++nt)
                acc[q][nt] = __builtin_amdgcn_mfma_f32_16x16x32_f16(
                    af, bf[ks * NT + nt], acc[q][nt], 0, 0, 0);
        }
    }

    // ---- epilogue: block-level LDS bounce per L, explicit barriers ----
    // write (wave-private rows) -> barrier -> coalesced copy -> barrier
#pragma unroll
    for (int L = 0; L <= Lmax; ++L) {
        const int L0 = L * L;
        const int stride = 2 * L + 1;
#pragma unroll
        for (int nt = 0; nt < NT; ++nt) {
            if (nt * 16 + 15 < L0 || nt * 16 > L0 + stride - 1) continue; // pruned
            const int n = nt * 16 + (lane & 15);
            const bool act = (n >= L0) && (n < L0 + stride);
            const int M = n - L0;
            const int rb = w * 64 + ((lane >> 4) << 2);
#pragma unroll
            for (int q = 0; q < 4; ++q)
#pragma unroll
                for (int r = 0; r < 4; ++r)
                    if (act) os[(rb + q * 16 + r) * stride + M] = acc[q][nt][r];
        }
        __syncthreads();
        const int chunk = L1 - FIRST_L1[L];
        float* __restrict__ dst = out + (size_t)BASE[L] * BC +
            ((size_t)(b * NCH[L] + chunk) * C_DIM + i0) * stride;
#pragma unroll
        for (int k0 = 0; k0 < 256 * 11; k0 += 256) {
            const int k = k0 + tid;
            if (k < 256 * stride) dst[k] = os[k];
        }
        __syncthreads();
    }
}

__global__ __launch_bounds__(256) void tp_all(
    const float* __restrict__ x0, const float* __restrict__ x1,
    const float* __restrict__ x2, const float* __restrict__ x3,
    const float* __restrict__ x4, const float* __restrict__ x5,
    const float* __restrict__ cg00, const _Float16* __restrict__ wsf,
    float* __restrict__ out) {
    __shared__ _Float16 Alds[256 * 40];              // 20480 B (K-loop A tiles)
    __shared__ __align__(16) float os[256 * 11];     // 11264 B (epilogue bounce)
    const int part = (int)blockIdx.x >> 10;    // 1024 blocks per part, heavy first
    const int blk  = (int)blockIdx.x & 1023;
    switch (part) {
        case 0: tp_mfma<5>(x5, wsf + 12 * 512, out, blk, Alds, os); break;
        case 1: tp_mfma<4>(x4, wsf + 6 * 512,  out, blk, Alds, os); break;
        case 2: tp_mfma<3>(x3, wsf + 3 * 512,  out, blk, Alds, os); break;
        case 3: tp_mfma<2>(x2, wsf + 1 * 512,  out, blk, Alds, os); break;
        case 4: tp_mfma<1>(x1, wsf + 0,        out, blk, Alds, os); break;
        default: {                              // l1 = 0: out = c00 * x0^2
            const int t = (blk << 8) + (int)threadIdx.x;
            const float v = x0[t];
            const int b = t >> 9, i = t & 511;
            out[(size_t)b * 3072 + i] = cg00[0] * v * v;
        } break;
    }
}

extern "C" void kernel_launch(void* const* d_in, const int* in_sizes, int n_in,
                              void* d_out, int out_size, void* d_ws, size_t ws_size,
                              hipStream_t stream) {
    (void)in_sizes; (void)n_in; (void)out_size; (void)ws_size;

    PrepArgs pa{};
    int idx = 6;
    for (int l1 = 0; l1 <= 5; ++l1) {
        const int Lmax = (2 * l1 < 5) ? 2 * l1 : 5;
        for (int L = 0; L <= Lmax; ++L) {
            if (l1 >= 1) pa.cg[l1 - 1][L] = (const float*)d_in[idx];
            ++idx;
        }
    }
    int f = 0;
    for (int l1 = 1; l1 <= 5; ++l1) {
        const int d = 2 * l1 + 1, NP = d * (d + 1) / 2;
        const int Lmax = (2 * l1 < 5) ? 2 * l1 : 5;
        const int Ntot = (Lmax + 1) * (Lmax + 1);
        const int KS = (NP + 31) / 32, NT = (Ntot + 15) / 16;
        for (int ks = 0; ks < KS; ++ks)
            for (int nt = 0; nt < NT; ++nt) {
                pa.l1[f] = l1; pa.ks[f] = ks; pa.nt[f] = nt; ++f;
            }
    }
    // f == 21 frags -> 21.5 KB fp16 table in ws

    hipLaunchKernelGGL(prep_frags, dim3(21), dim3(512), 0, stream,
                       pa, (_Float16*)d_ws);
    hipLaunchKernelGGL(tp_all, dim3(6 * 1024), dim3(256), 0, stream,
                       (const float*)d_in[0], (const float*)d_in[1],
                       (const float*)d_in[2], (const float*)d_in[3],
                       (const float*)d_in[4], (const float*)d_in[5],
                       (const float*)d_in[6], (const _Float16*)d_ws,
                       (float*)d_out);
}